// Round 7
// baseline (277.530 us; speedup 1.0000x reference)
//
#include <hip/hip_runtime.h>
#include <hip/hip_bf16.h>

// AttentionDownsample: B=256, N=196(14x14), NQ=49(7x7 stride2), IN=384,
// HEADS=12, KEY=16, VAL=32, KV=576, OUT=512.
// Contract (verified R8): inputs fp32, bias_idxs int32, output fp32.
// R12: GEMM staging via global_load_lds w=16. 319.4us.
// R13: attn LDS 40448 (4 blk/CU), conflict strides, exp2 softmax. 309.9us.
// R14: bias as MFMA C-in, unnormalized P. 277.4us (kv 61us).
// R15: 2-phase dbuf + __syncthreads = NEUTRAL — syncthreads drains vmcnt(0),
//      loads never span the barrier (T4 lesson).
// R16: W direct-to-VGPR REGRESSED (FETCH 59->156MB). DMA staging is the
//      HBM-minimal path.
// R17: BK=64 small win (271.4, kv 59.5) but parity swizzle tripled bank
//      conflicts (8.1M) and doubled VALU. Reverting layout.
// R18 (this round): T3+T4 proper — 3-deep pipeline, ONE raw s_barrier per
// k-step, counted s_waitcnt vmcnt(16/8/0) so loads span ~2 compute phases.
// vmcnt is per-wave => every wave reads only self-staged data: A self-staged
// (as before), W DUPLICATE-staged by both waves (same bytes, same LDS addr,
// benign; W is L2-resident). BK=32, 64B rows (R14 conflict level).

typedef __bf16 bf16;
typedef float f32x4 __attribute__((ext_vector_type(4)));
typedef __bf16 bf16x8 __attribute__((ext_vector_type(8)));
typedef __bf16 bf16x4 __attribute__((ext_vector_type(4)));

// per-(b,h) kv2 block: k [196][16] el at +0, vT [32][196] el at +6272 B
#define KV2_BLK 18816
#define KV2_VOFF 6272
#define Q2_BLK 1568
#define LOG2E 1.4426950408889634f
#define QSCALE 0.36067376022224085f  // 0.25 * log2e

// async global->LDS, 16B per lane. LDS dest is wave-uniform base + lane*16
// (m104); global src is per-lane (gather-safe, m173). Size must be literal.
__device__ __forceinline__ void gl2lds16(const bf16* g, bf16* l) {
  __builtin_amdgcn_global_load_lds(
      (const __attribute__((address_space(1))) void*)g,
      (__attribute__((address_space(3))) void*)l, 16, 0, 0);
}

// ---------------------------------------------------------------------------
__global__ void cast_kernel(const float* __restrict__ src, bf16* __restrict__ dst, long n) {
  long i = ((long)blockIdx.x * 256 + threadIdx.x) * 8;
  if (i + 8 <= n) {
    f32x4 lo = *(const f32x4*)(src + i), hi = *(const f32x4*)(src + i + 4);
    bf16x8 t;
    t[0]=(bf16)lo[0]; t[1]=(bf16)lo[1]; t[2]=(bf16)lo[2]; t[3]=(bf16)lo[3];
    t[4]=(bf16)hi[0]; t[5]=(bf16)hi[1]; t[6]=(bf16)hi[2]; t[7]=(bf16)hi[3];
    *(bf16x8*)(dst + i) = t;
  }
}

// merged weight casts: kv_w 221184 | q_w 73728 | pj_w 196608 (all %8==0)
__global__ void wcast_kernel(const float* __restrict__ kv_w, const float* __restrict__ q_w,
                             const float* __restrict__ pj_w, bf16* __restrict__ kvwb,
                             bf16* __restrict__ qwb, bf16* __restrict__ pjwb) {
  long i = ((long)blockIdx.x * 256 + threadIdx.x) * 8;
  const float* s; bf16* d; long off;
  if (i < 221184)      { s = kv_w; d = kvwb; off = 0; }
  else if (i < 294912) { s = q_w;  d = qwb;  off = 221184; }
  else if (i < 491520) { s = pj_w; d = pjwb; off = 294912; }
  else return;
  long j = i - off;
  f32x4 lo = *(const f32x4*)(s + j), hi = *(const f32x4*)(s + j + 4);
  bf16x8 t;
  t[0]=(bf16)lo[0]; t[1]=(bf16)lo[1]; t[2]=(bf16)lo[2]; t[3]=(bf16)lo[3];
  t[4]=(bf16)hi[0]; t[5]=(bf16)hi[1]; t[6]=(bf16)hi[2]; t[7]=(bf16)hi[3];
  *(bf16x8*)(d + j) = t;
}

// ---------------------------------------------------------------------------
// q-range scale/shift get *QSCALE so attn scores are already in exp2 domain.
__global__ void prep_kernel(const float* kv_g, const float* kv_b, const float* kv_m, const float* kv_v,
                            const float* q_g,  const float* q_b,  const float* q_m,  const float* q_v,
                            const float* p_g,  const float* p_b,  const float* p_m,  const float* p_v,
                            float* scbuf) {
  int i = blockIdx.x * 256 + threadIdx.x;
  const float *g, *bb, *mm, *vv;
  float *sc, *sh;
  int c;
  float f = 1.0f;
  if (i < 576)        { c = i;       g = kv_g; bb = kv_b; mm = kv_m; vv = kv_v; sc = scbuf;        sh = scbuf + 576;  }
  else if (i < 768)   { c = i - 576; g = q_g;  bb = q_b;  mm = q_m;  vv = q_v;  sc = scbuf + 1152; sh = scbuf + 1344; f = QSCALE; }
  else if (i < 1280)  { c = i - 768; g = p_g;  bb = p_b;  mm = p_m;  vv = p_v;  sc = scbuf + 1536; sh = scbuf + 2048; }
  else return;
  float sv = g[c] * rsqrtf(vv[c] + 1e-5f);
  sc[c] = sv * f;
  sh[c] = (bb[c] - mm[c] * sv) * f;
}

// ---------------------------------------------------------------------------
// biasp2: MFMA C-fragment layout [h][wid][jt][lane] f32x4.
// reg r = wid*16 + quad*4 + reg, col c = jt*16 + mrow. Mask c>=196 -> -1e30
// (exp2(-1e30 - mx) == 0 handles softmax masking for free). log2e baked in.
__global__ void bias_kernel(const float* biases, const int* idxs, float* biasp2) {
  int i = blockIdx.x * 256 + threadIdx.x;   // 12*4*13*64 = 39936 frags
  if (i >= 39936) return;
  int lane = i & 63;
  int jt   = (i >> 6) % 13;
  int hw   = i / (13 * 64);                 // h*4 + wid
  int wid  = hw & 3;
  int h    = hw >> 2;
  int mrow = lane & 15, quad = lane >> 4;
  int c = jt * 16 + mrow;
  f32x4 v;
#pragma unroll
  for (int reg = 0; reg < 4; ++reg) {
    int r = wid * 16 + quad * 4 + reg;
    float val;
    if (c >= 196)      val = -1e30f;
    else if (r < 49)   val = biases[h * 196 + idxs[r * 196 + c]] * LOG2E;
    else               val = 0.0f;
    v[reg] = val;
  }
  ((f32x4*)biasp2)[i] = v;
}

// ---------------------------------------------------------------------------
// GEMM C = A[M,384] @ W[N,384]^T, BN epilogue. A, W bf16.
// Tile 128x64, 128 threads (2 waves), wave does 64x64 via 4x4 mfma 16x16x32.
// GRID IS M-MAJOR: m0 = blockIdx.x*128, n0 = blockIdx.y*64 (XCD L2 locality).
// Staging (R18): gl2lds w=16, 3 LDS buffers (36 KB), BK=32. Per k-step:
//   s_barrier; STAGE(tile t+2); s_waitcnt vmcnt(16|8|0); ds_read+MFMA.
// One barrier per k-step; counted vmcnt lets tile t+1/t+2 loads stay in
// flight ACROSS the barrier (~2 compute phases to land). Per-wave vmcnt =>
// each wave reads only self-staged LDS: A self-staged (4 issues), W
// duplicate-staged by both waves (4 issues; same bytes + LDS addrs, benign).
// Overwrite safety: STAGE at iter t targets buf (t-1)%3, last read at t-1;
// the top-of-t barrier orders all waves past those reads.
// EPI: 0 = fp32 C (pj) | 1 = kv scatter | 2 = q scatter.
// GATHER: A-row m -> x row b*196 + (qq/7)*28 + (qq%7)*2 (per-lane src ok).
template<int EPI, bool GATHER>
__global__ __launch_bounds__(128)
void gemm_bn_kernel(const bf16* __restrict__ A, const bf16* __restrict__ W,
                    const float* __restrict__ sc, const float* __restrict__ sh,
                    char* __restrict__ out, int N) {
  __shared__ __attribute__((aligned(16))) bf16 As[3 * 128 * 32];  // 24 KB
  __shared__ __attribute__((aligned(16))) bf16 Ws[3 * 64 * 32];   // 12 KB
  const int tid  = threadIdx.x;
  const int lane = tid & 63;
  const int wid  = tid >> 6;
  const int m0 = blockIdx.x * 128;   // m-major dispatch
  const int n0 = blockIdx.y * 64;
  const int rquad = lane >> 2;       // row within a 16-row load chunk
  const int kslot = lane & 3;        // which 8-elem k-group (16 B)
  const int mrow = lane & 15;
  const int quad = lane >> 4;

  // A: wave stages its own 64 rows (4 chunks x 16 rows)
  long gA[4]; int lA[4];
#pragma unroll
  for (int i = 0; i < 4; ++i) {
    int rt = wid * 64 + i * 16 + rquad;
    long arow;
    if (GATHER) {
      int m = m0 + rt;
      int b = m / 49;
      int qq = m - b * 49;
      arow = (long)b * 196 + (qq / 7) * 28 + (qq % 7) * 2;
    } else {
      arow = m0 + rt;
    }
    gA[i] = arow * 384 + kslot * 8;
    lA[i] = (wid * 64 + i * 16) * 32;
  }
  // W: BOTH waves stage all 64 rows (duplicate; self-contained per-wave vmcnt)
  long gW[4]; int lW[4];
#pragma unroll
  for (int j = 0; j < 4; ++j) {
    int rt = j * 16 + rquad;
    gW[j] = (long)(n0 + rt) * 384 + kslot * 8;
    lW[j] = (j * 16) * 32;
  }

  f32x4 acc[4][4] = {};

#define STAGE_T(buf, t)                                                     \
  do {                                                                      \
    const long kg_ = (long)(t) * 32;                                        \
    _Pragma("unroll")                                                       \
    for (int i_ = 0; i_ < 4; ++i_)                                          \
      gl2lds16(A + gA[i_] + kg_, As + (buf) * 4096 + lA[i_]);               \
    _Pragma("unroll")                                                       \
    for (int j_ = 0; j_ < 4; ++j_)                                          \
      gl2lds16(W + gW[j_] + kg_, Ws + (buf) * 2048 + lW[j_]);               \
  } while (0)

  STAGE_T(0, 0);
  STAGE_T(1, 1);

#pragma unroll
  for (int t = 0; t < 12; ++t) {
    asm volatile("s_barrier" ::: "memory");   // all waves past t-1 reads
    if (t + 2 < 12) STAGE_T((t + 2) % 3, t + 2);
    if (t < 10)       asm volatile("s_waitcnt vmcnt(16)" ::: "memory");
    else if (t == 10) asm volatile("s_waitcnt vmcnt(8)"  ::: "memory");
    else              asm volatile("s_waitcnt vmcnt(0)"  ::: "memory");
    const int ca = (t % 3) * 4096;
    const int cw = (t % 3) * 2048;
    bf16x8 af[4], bw[4];
#pragma unroll
    for (int mi = 0; mi < 4; ++mi)
      af[mi] = *(const bf16x8*)(As + ca + (wid * 64 + mi * 16 + mrow) * 32 + quad * 8);
#pragma unroll
    for (int ni = 0; ni < 4; ++ni)
      bw[ni] = *(const bf16x8*)(Ws + cw + (ni * 16 + mrow) * 32 + quad * 8);
#pragma unroll
    for (int mi = 0; mi < 4; ++mi)
#pragma unroll
      for (int ni = 0; ni < 4; ++ni)
        acc[mi][ni] = __builtin_amdgcn_mfma_f32_16x16x32_bf16(af[mi], bw[ni], acc[mi][ni], 0, 0, 0);
  }
#undef STAGE_T

  // epilogue: C/D layout col=lane&15, row=quad*4+reg (m89-verified)
#pragma unroll
  for (int ni = 0; ni < 4; ++ni) {
    int col = n0 + ni * 16 + mrow;
    float s = sc[col], t = sh[col];
    int h = 0, dd = 0;
    if (EPI == 1) { h = col / 48; dd = col - h * 48; }
    if (EPI == 2) { h = col >> 4; dd = col & 15; }
#pragma unroll
    for (int mi = 0; mi < 4; ++mi) {
      int mbase = m0 + wid * 64 + mi * 16 + quad * 4;
      if (EPI == 0) {
#pragma unroll
        for (int reg = 0; reg < 4; ++reg) {
          int m = mbase + reg;
          ((float*)out)[(long)m * N + col] = acc[mi][ni][reg] * s + t;
        }
      } else if (EPI == 1) {
        // 196 % 4 == 0 and mbase % 4 == 0 -> all 4 regs share b; j consecutive
        int b = mbase / 196, j = mbase - b * 196;
        char* base = out + ((long)(b * 12 + h)) * KV2_BLK;
        if (dd < 16) {
#pragma unroll
          for (int reg = 0; reg < 4; ++reg)
            ((bf16*)base)[(j + reg) * 16 + dd] = (bf16)(acc[mi][ni][reg] * s + t);
        } else {
          bf16x4 tv;
#pragma unroll
          for (int reg = 0; reg < 4; ++reg)
            tv[reg] = (bf16)(acc[mi][ni][reg] * s + t);
          *(bf16x4*)((bf16*)(base + KV2_VOFF) + (dd - 16) * 196 + j) = tv;
        }
      } else {
#pragma unroll
        for (int reg = 0; reg < 4; ++reg) {
          int m = mbase + reg;
          int b = m / 49, qq = m - b * 49;  // 49 % 4 != 0: per-reg b
          ((bf16*)(out + ((long)(b * 12 + h)) * Q2_BLK))[qq * 16 + dd] = (bf16)(acc[mi][ni][reg] * s + t);
        }
      }
    }
  }
}

// ---------------------------------------------------------------------------
// Fused MFMA attention, one block per (b,h). 256 threads (4 waves).
// LDS 40448 B => 4 blocks/CU:
//   vT_s [32][200] @0 (12800 B)   conflict-free b128 reads
//   k_s  [208][40] @12800 (16640) conflict-free
//   P_s  [64][216] @12800 (27648) overlays k_s post-QK
// Q direct to A-frag regs. Bias arrives as pre-arranged C-frags (biasp2),
// mask baked in as -1e30 => QK is mfma(aq,bk,cb). P unnormalized; 1/sum
// applied to the 8 output values.
__global__ __launch_bounds__(256, 4)
void attn_kernel(const char* __restrict__ kv2, const char* __restrict__ qb2,
                 const float* __restrict__ biasp2, bf16* __restrict__ aout) {
  __shared__ __attribute__((aligned(16))) char smem[40448];
  bf16* vT_s = (bf16*)smem;            // [32][200]
  bf16* k_s  = (bf16*)(smem + 12800);  // [208][40], cols 0-15 data, 16-31 zero
  bf16* P_s  = (bf16*)(smem + 12800);  // [64][216] overlay (post-QK)

  const int bh = blockIdx.x;
  const int b = bh / 12;
  const int h = bh - b * 12;
  const int tid  = threadIdx.x;
  const int lane = tid & 63;
  const int wid  = tid >> 6;
  const int mrow = lane & 15;
  const int quad = lane >> 4;

  const bf16* ksrc = (const bf16*)(kv2 + (long)bh * KV2_BLK);
  const bf16* vsrc = (const bf16*)(kv2 + (long)bh * KV2_BLK + KV2_VOFF);
  const bf16* qsrc = (const bf16*)(qb2 + (long)bh * Q2_BLK);

  bf16x8 z = {};
  // Q A-fragment + bias C-frags issued first (coalesced; latency hides
  // under the LDS staging below).
  const int qrow = wid * 16 + mrow;
  bf16x8 aq = (quad < 2 && qrow < 49)
                  ? *(const bf16x8*)(qsrc + qrow * 16 + quad * 8) : z;
  f32x4 cb[13];
  {
    const f32x4* bf2 = (const f32x4*)biasp2 + ((long)(h * 4 + wid) * 13 * 64 + lane);
#pragma unroll
    for (int jt = 0; jt < 13; ++jt) cb[jt] = bf2[jt * 64];
  }

  {
    // k: 208 rows x 4 chunks of bf16x8 (cols 16-31 zeroed, 32-39 unread)
    for (int i = tid; i < 832; i += 256) {
      int r = i >> 2, c = i & 3;
      *(bf16x8*)(k_s + r * 40 + c * 8) =
          (r < 196 && c < 2) ? *(const bf16x8*)(ksrc + r * 16 + c * 8) : z;
    }
    // vT: 32 rows x 50 chunks of bf16x4 (cols 196-199 zeroed)
    bf16x4 z4 = {};
    for (int i = tid; i < 1600; i += 256) {
      int r = i / 50, c = i - r * 50;
      *(bf16x4*)(vT_s + r * 200 + c * 4) =
          (c < 49) ? *(const bf16x4*)(vsrc + r * 196 + c * 4) : z4;
    }
  }
  __syncthreads();

  // QK^T: 13 n-tiles of 16 keys, bias as C-in (mask included)
  f32x4 s[13];
#pragma unroll
  for (int jt = 0; jt < 13; ++jt) {
    bf16x8 bk = *(const bf16x8*)(k_s + (jt * 16 + mrow) * 40 + quad * 8);
    s[jt] = __builtin_amdgcn_mfma_f32_16x16x32_bf16(aq, bk, cb[jt], 0, 0, 0);
  }

  const int rbase = wid * 16 + quad * 4;
  float mx[4], sm[4];
#pragma unroll
  for (int reg = 0; reg < 4; ++reg) {
    float m = -1e30f;
#pragma unroll
    for (int jt = 0; jt < 13; ++jt) m = fmaxf(m, s[jt][reg]);
    m = fmaxf(m, __shfl_xor(m, 1));
    m = fmaxf(m, __shfl_xor(m, 2));
    m = fmaxf(m, __shfl_xor(m, 4));
    m = fmaxf(m, __shfl_xor(m, 8));
    mx[reg] = m;
  }
#pragma unroll
  for (int jt = 0; jt < 13; ++jt)
#pragma unroll
    for (int reg = 0; reg < 4; ++reg)
      s[jt][reg] = __builtin_amdgcn_exp2f(s[jt][reg] - mx[reg]);  // masked -> 0
#pragma unroll
  for (int reg = 0; reg < 4; ++reg) {
    float t = 0.0f;
#pragma unroll
    for (int jt = 0; jt < 13; ++jt) t += s[jt][reg];
    t += __shfl_xor(t, 1);
    t += __shfl_xor(t, 2);
    t += __shfl_xor(t, 4);
    t += __shfl_xor(t, 8);
    sm[reg] = 1.0f / t;
  }

  __syncthreads();  // all waves done with k_s before P overlay writes

  // P (unnormalized): cols 0-207 written (196-207 are exp2(masked) = 0)
  bf16* Pw = P_s + wid * 16 * 216;
#pragma unroll
  for (int jt = 0; jt < 13; ++jt) {
#pragma unroll
    for (int reg = 0; reg < 4; ++reg)
      Pw[(quad * 4 + reg) * 216 + jt * 16 + mrow] = (bf16)s[jt][reg];
  }

  f32x4 o[2] = {};
#pragma unroll
  for (int kk = 0; kk < 6; ++kk) {
    bf16x8 ap = *(const bf16x8*)(Pw + mrow * 216 + kk * 32 + quad * 8);
#pragma unroll
    for (int nt = 0; nt < 2; ++nt) {
      bf16x8 bv = *(const bf16x8*)(vT_s + (nt * 16 + mrow) * 200 + kk * 32 + quad * 8);
      o[nt] = __builtin_amdgcn_mfma_f32_16x16x32_bf16(ap, bv, o[nt], 0, 0, 0);
    }
  }
  {  // kk=6: keys 192-199 only (quad 0); other quads contribute zero
    bf16x8 ap = (quad == 0) ? *(const bf16x8*)(Pw + mrow * 216 + 192) : z;
#pragma unroll
    for (int nt = 0; nt < 2; ++nt) {
      bf16x8 bv = (quad == 0) ? *(const bf16x8*)(vT_s + (nt * 16 + mrow) * 200 + 192) : z;
      o[nt] = __builtin_amdgcn_mfma_f32_16x16x32_bf16(ap, bv, o[nt], 0, 0, 0);
    }
  }

#pragma unroll
  for (int nt = 0; nt < 2; ++nt) {
#pragma unroll
    for (int reg = 0; reg < 4; ++reg) {
      int r = rbase + reg;
      if (r < 49) {
        float x = o[nt][reg] * sm[reg];   // normalization folded here
        float sil = x / (1.0f + __expf(-x));
        aout[((long)b * 49 + r) * 384 + h * 32 + nt * 16 + mrow] = (bf16)sil;
      }
    }
  }
}

// ---------------------------------------------------------------------------
extern "C" void kernel_launch(void* const* d_in, const int* in_sizes, int n_in,
                              void* d_out, int out_size, void* d_ws, size_t ws_size,
                              hipStream_t stream) {
  const float* x      = (const float*)d_in[0];
  const float* kv_w   = (const float*)d_in[1];
  const float* q_w    = (const float*)d_in[6];
  const float* pj_w   = (const float*)d_in[11];
  const float* biases = (const float*)d_in[16];
  const int*   bidx   = (const int*)d_in[17];

  char* ws = (char*)d_ws;
  float* scbuf = (float*)ws;                  // 2560 f32
  char*  qb2   = ws + 471296;                 // 3072 x 1568 B
  bf16*  aout  = (bf16*)(ws + 5288192);       // (12544,384) bf16
  bf16*  xb    = (bf16*)(ws + 14921984);      // (50176,384) bf16 = 38.5 MB
  bf16*  kvwb  = (bf16*)(ws + 53457152);      // (576,384) bf16
  bf16*  qwb   = (bf16*)(ws + 53899520);      // (192,384) bf16
  bf16*  pjwb  = (bf16*)(ws + 54046976);      // (512,384) bf16
  char*  kv2   = ws + 54440192;               // 3072 x 18816 B = 57.8 MB
  float* biasp2= (float*)(ws + 112242944);    // 39936 f32x4 = 639 KB
                                              // end: ~112.9 MB (< ~300 MB ws)

  // casts: x (big) + merged weights (one launch)
  cast_kernel<<<9408, 256, 0, stream>>>(x, xb, 19267584L);
  wcast_kernel<<<240, 256, 0, stream>>>(kv_w, q_w, pj_w, kvwb, qwb, pjwb);

  prep_kernel<<<5, 256, 0, stream>>>(
      (const float*)d_in[2],  (const float*)d_in[3],  (const float*)d_in[4],  (const float*)d_in[5],
      (const float*)d_in[7],  (const float*)d_in[8],  (const float*)d_in[9],  (const float*)d_in[10],
      (const float*)d_in[12], (const float*)d_in[13], (const float*)d_in[14], (const float*)d_in[15],
      scbuf);
  bias_kernel<<<156, 256, 0, stream>>>(biases, bidx, biasp2);

  // q = BN(xq @ q_w^T) * 0.25*log2e: M=12544 gathered, N=192 (m-major grid)
  gemm_bn_kernel<2, true><<<dim3(98, 3), 128, 0, stream>>>(
      xb, qwb, scbuf + 1152, scbuf + 1344, qb2, 192);

  // kv = BN(x @ kv_w^T): M=50176, N=576 (m-major grid)
  gemm_bn_kernel<1, false><<<dim3(392, 9), 128, 0, stream>>>(
      xb, kvwb, scbuf, scbuf + 576, kv2, 576);

  // fused attention per (b,h)
  attn_kernel<<<3072, 256, 0, stream>>>(kv2, qb2, biasp2, aout);

  // out = BN(silu_attn @ pj_w^T): M=12544, N=512, fp32 out (m-major grid)
  gemm_bn_kernel<0, false><<<dim3(98, 8), 128, 0, stream>>>(
      aout, pjwb, scbuf + 1536, scbuf + 2048, (char*)d_out, 512);
}

// Round 9
// 260.322 us; speedup vs baseline: 1.0661x; 1.0661x over previous
//
#include <hip/hip_runtime.h>
#include <hip/hip_bf16.h>

// AttentionDownsample: B=256, N=196(14x14), NQ=49(7x7 stride2), IN=384,
// HEADS=12, KEY=16, VAL=32, KV=576, OUT=512.
// Contract (verified R8): inputs fp32, bias_idxs int32, output fp32.
// R12: GEMM staging via global_load_lds w=16. 319.4us.
// R13: attn LDS 40448 (4 blk/CU), conflict strides, exp2 softmax. 309.9us.
// R14: bias as MFMA C-in, unnormalized P. 277.4us (kv 61us).
// R15: 2-phase dbuf NEUTRAL. R16: W->VGPR REGRESSED (FETCH 3x). R18:
// counted-vmcnt 3-deep REGRESSED (64.8 kv, occ 17%). Conclusion: at K=384
// (6-12 k-steps) schedule micro-opt is null; conflicts only ~7% of cycles.
// R17 BEST: BK=64 + parity swizzle, 271.4us (kv 59.5).
// R19/R20 (this round; R19 bench never ran — GPU timeout; resubmit with
// dead placeholder removed): LAUNCH-GRAPH compression 8 -> 4 kernels.
// Sum of parts (~170us) << total (271) => inter-kernel bubbles + drain
// tails dominate the residual. (1) one setup kernel (x-cast || wcast ||
// prep || bias); (2) kv+q GEMMs merged into ONE dispatch dim3(392,12)
// (runtime mode, block-uniform role; q's 294 blocks fill latency-idle
// slots during kv); (3) attn; (4) pj via same gemm kernel (mode 0).
// GEMM internals = R17 (measured best).

typedef __bf16 bf16;
typedef float f32x4 __attribute__((ext_vector_type(4)));
typedef __bf16 bf16x8 __attribute__((ext_vector_type(8)));
typedef __bf16 bf16x4 __attribute__((ext_vector_type(4)));

// per-(b,h) kv2 block: k [196][16] el at +0, vT [32][196] el at +6272 B
#define KV2_BLK 18816
#define KV2_VOFF 6272
#define Q2_BLK 1568
#define LOG2E 1.4426950408889634f
#define QSCALE 0.36067376022224085f  // 0.25 * log2e

// async global->LDS, 16B per lane. LDS dest is wave-uniform base + lane*16
// (m104); global src is per-lane (gather/swizzle-safe, m173). Size literal.
__device__ __forceinline__ void gl2lds16(const bf16* g, bf16* l) {
  __builtin_amdgcn_global_load_lds(
      (const __attribute__((address_space(1))) void*)g,
      (__attribute__((address_space(3))) void*)l, 16, 0, 0);
}

__device__ __forceinline__ void cast8(const float* s, bf16* d, long i) {
  f32x4 lo = *(const f32x4*)(s + i), hi = *(const f32x4*)(s + i + 4);
  bf16x8 t;
  t[0]=(bf16)lo[0]; t[1]=(bf16)lo[1]; t[2]=(bf16)lo[2]; t[3]=(bf16)lo[3];
  t[4]=(bf16)hi[0]; t[5]=(bf16)hi[1]; t[6]=(bf16)hi[2]; t[7]=(bf16)hi[3];
  *(bf16x8*)(d + i) = t;
}

// ---------------------------------------------------------------------------
// setup: blocks [0,9408) x-cast | [9408,9648) weight casts | [9648,9653)
// prep (BN fold; q gets *QSCALE) | [9653,9809) biasp2 C-frag pre-arrange.
__global__ void setup_kernel(
    const float* __restrict__ x, bf16* __restrict__ xb,
    const float* __restrict__ kv_w, const float* __restrict__ q_w,
    const float* __restrict__ pj_w, bf16* __restrict__ kvwb,
    bf16* __restrict__ qwb, bf16* __restrict__ pjwb,
    const float* kv_g, const float* kv_b, const float* kv_m, const float* kv_v,
    const float* q_g,  const float* q_b,  const float* q_m,  const float* q_v,
    const float* p_g,  const float* p_b,  const float* p_m,  const float* p_v,
    float* scbuf, const float* biases, const int* idxs, float* biasp2) {
  const int blk = blockIdx.x, tid = threadIdx.x;
  if (blk < 9408) {                       // x cast: 9408*256*8 = 19267584
    cast8(x, xb, ((long)blk * 256 + tid) * 8);
  } else if (blk < 9648) {                // weight casts: 240*256*8 = 491520
    long i = ((long)(blk - 9408) * 256 + tid) * 8;
    const float* s; bf16* d; long off;
    if (i < 221184)      { s = kv_w; d = kvwb; off = 0; }
    else if (i < 294912) { s = q_w;  d = qwb;  off = 221184; }
    else                 { s = pj_w; d = pjwb; off = 294912; }
    cast8(s, d, i - off);
  } else if (blk < 9653) {                // prep: 5*256 = 1280
    int i = (blk - 9648) * 256 + tid;
    const float *g, *bb, *mm, *vv; float *sc, *sh; int c; float f = 1.0f;
    if (i < 576)       { c = i;       g = kv_g; bb = kv_b; mm = kv_m; vv = kv_v; sc = scbuf;        sh = scbuf + 576;  }
    else if (i < 768)  { c = i - 576; g = q_g;  bb = q_b;  mm = q_m;  vv = q_v;  sc = scbuf + 1152; sh = scbuf + 1344; f = QSCALE; }
    else if (i < 1280) { c = i - 768; g = p_g;  bb = p_b;  mm = p_m;  vv = p_v;  sc = scbuf + 1536; sh = scbuf + 2048; }
    else return;
    float sv = g[c] * rsqrtf(vv[c] + 1e-5f);
    sc[c] = sv * f;
    sh[c] = (bb[c] - mm[c] * sv) * f;
  } else {                                // biasp2: 156*256 = 39936 frags
    int i = (blk - 9653) * 256 + tid;
    if (i >= 39936) return;
    int lane = i & 63;
    int jt   = (i >> 6) % 13;
    int hw   = i / (13 * 64);
    int wid  = hw & 3;
    int h    = hw >> 2;
    int mrow = lane & 15, quad = lane >> 4;
    int c = jt * 16 + mrow;
    f32x4 v;
#pragma unroll
    for (int reg = 0; reg < 4; ++reg) {
      int r = wid * 16 + quad * 4 + reg;
      float val;
      if (c >= 196)      val = -1e30f;
      else if (r < 49)   val = biases[h * 196 + idxs[r * 196 + c]] * LOG2E;
      else               val = 0.0f;
      v[reg] = val;
    }
    ((f32x4*)biasp2)[i] = v;
  }
}

// ---------------------------------------------------------------------------
// GEMM C = A[M,384] @ W[N,384]^T, BN epilogue (R17 internals: BK=64, parity
// XOR swizzle, single LDS buffer, 2 syncthreads per k-step, 6 k-steps).
// mode 1: merged kv+q — y<9: kv (EPI1), y>=9: q (EPI2, gather, x<98 only).
// mode 0: pj (EPI0, fp32 out, N=N0). Role resolution is block-uniform.
__global__ __launch_bounds__(128)
void gemm_bn_kernel(int mode, const bf16* __restrict__ A,
                    const bf16* __restrict__ W0, const bf16* __restrict__ W1,
                    const float* __restrict__ sc0, const float* __restrict__ sh0,
                    const float* __restrict__ sc1, const float* __restrict__ sh1,
                    char* __restrict__ out0, char* __restrict__ out1, int N0) {
  int epi, n0; bool gather;
  const bf16* W; const float* sc; const float* sh; char* out; int N;
  if (mode == 0) {
    epi = 0; gather = false; n0 = blockIdx.y * 64;
    W = W0; sc = sc0; sh = sh0; out = out0; N = N0;
  } else if (blockIdx.y < 9) {
    epi = 1; gather = false; n0 = blockIdx.y * 64;
    W = W0; sc = sc0; sh = sh0; out = out0; N = 576;
  } else {
    if (blockIdx.x >= 98) return;
    epi = 2; gather = true; n0 = (blockIdx.y - 9) * 64;
    W = W1; sc = sc1; sh = sh1; out = out1; N = 192;
  }

  __shared__ __attribute__((aligned(16))) bf16 As[128 * 64];   // 16 KB
  __shared__ __attribute__((aligned(16))) bf16 Ws[64 * 64];    //  8 KB
  const int tid  = threadIdx.x;
  const int lane = tid & 63;
  const int wid  = tid >> 6;
  const int m0 = blockIdx.x * 128;   // m-major dispatch
  const int r8 = lane >> 3;          // row within an 8-row load chunk
  const int c8 = lane & 7;           // 16B col slot within the 128B row
  const int csw = (c8 ^ ((r8 & 1) << 2)) * 8;  // swizzled source col (els)
  const int mrow = lane & 15;
  const int quad = lane >> 4;

  // A staging: 8 chunks x 8 rows (wave stages its own 64 rows)
  long gA[8]; int lA[8];
#pragma unroll
  for (int i = 0; i < 8; ++i) {
    int rt = wid * 64 + i * 8 + r8;
    long arow;
    if (gather) {
      int m = m0 + rt;
      int b = m / 49;
      int qq = m - b * 49;
      arow = (long)b * 196 + (qq / 7) * 28 + (qq % 7) * 2;
    } else {
      arow = m0 + rt;
    }
    gA[i] = arow * 384 + csw;
    lA[i] = (wid * 64 + i * 8) * 64;
  }
  // W staging: 4 chunks x 8 rows (wave stages its own 32 rows)
  long gW[4]; int lW[4];
#pragma unroll
  for (int j = 0; j < 4; ++j) {
    int rt = wid * 32 + j * 8 + r8;
    gW[j] = (long)(n0 + rt) * 384 + csw;
    lW[j] = (wid * 32 + j * 8) * 64;
  }

  f32x4 acc[4][4] = {};
  // read-side swizzled slot offsets for k-half s=0/1 (per-lane constants)
  const int rd0 = ((0 * 4 + quad) ^ ((mrow & 1) << 2)) * 8;
  const int rd1 = ((1 * 4 + quad) ^ ((mrow & 1) << 2)) * 8;

  for (int t = 0; t < 6; ++t) {
    const long kg = (long)t * 64;
#pragma unroll
    for (int i = 0; i < 8; ++i) gl2lds16(A + gA[i] + kg, As + lA[i]);
#pragma unroll
    for (int j = 0; j < 4; ++j) gl2lds16(W + gW[j] + kg, Ws + lW[j]);
    __syncthreads();   // drains vmcnt(0): staged data complete + visible

#pragma unroll
    for (int s = 0; s < 2; ++s) {
      const int rds = s ? rd1 : rd0;
      bf16x8 af[4], bw[4];
#pragma unroll
      for (int mi = 0; mi < 4; ++mi)
        af[mi] = *(const bf16x8*)(As + (wid * 64 + mi * 16 + mrow) * 64 + rds);
#pragma unroll
      for (int ni = 0; ni < 4; ++ni)
        bw[ni] = *(const bf16x8*)(Ws + (ni * 16 + mrow) * 64 + rds);
#pragma unroll
      for (int mi = 0; mi < 4; ++mi)
#pragma unroll
        for (int ni = 0; ni < 4; ++ni)
          acc[mi][ni] = __builtin_amdgcn_mfma_f32_16x16x32_bf16(af[mi], bw[ni], acc[mi][ni], 0, 0, 0);
    }
    __syncthreads();   // all waves done reading before next-step overwrite
  }

  // epilogue: C/D layout col=lane&15, row=quad*4+reg (m89-verified)
#pragma unroll
  for (int ni = 0; ni < 4; ++ni) {
    int col = n0 + ni * 16 + mrow;
    float s = sc[col], t = sh[col];
    int h = 0, dd = 0;
    if (epi == 1) { h = col / 48; dd = col - h * 48; }
    if (epi == 2) { h = col >> 4; dd = col & 15; }
#pragma unroll
    for (int mi = 0; mi < 4; ++mi) {
      int mbase = m0 + wid * 64 + mi * 16 + quad * 4;
      if (epi == 0) {
#pragma unroll
        for (int reg = 0; reg < 4; ++reg) {
          int m = mbase + reg;
          ((float*)out)[(long)m * N + col] = acc[mi][ni][reg] * s + t;
        }
      } else if (epi == 1) {
        // 196 % 4 == 0 and mbase % 4 == 0 -> all 4 regs share b; j consecutive
        int b = mbase / 196, j = mbase - b * 196;
        char* base = out + ((long)(b * 12 + h)) * KV2_BLK;
        if (dd < 16) {
#pragma unroll
          for (int reg = 0; reg < 4; ++reg)
            ((bf16*)base)[(j + reg) * 16 + dd] = (bf16)(acc[mi][ni][reg] * s + t);
        } else {
          bf16x4 tv;
#pragma unroll
          for (int reg = 0; reg < 4; ++reg)
            tv[reg] = (bf16)(acc[mi][ni][reg] * s + t);
          *(bf16x4*)((bf16*)(base + KV2_VOFF) + (dd - 16) * 196 + j) = tv;
        }
      } else {
#pragma unroll
        for (int reg = 0; reg < 4; ++reg) {
          int m = mbase + reg;
          int b = m / 49, qq = m - b * 49;  // 49 % 4 != 0: per-reg b
          ((bf16*)(out + ((long)(b * 12 + h)) * Q2_BLK))[qq * 16 + dd] = (bf16)(acc[mi][ni][reg] * s + t);
        }
      }
    }
  }
}

// ---------------------------------------------------------------------------
// Fused MFMA attention, one block per (b,h). 256 threads (4 waves).
// LDS 40448 B => 4 blocks/CU:
//   vT_s [32][200] @0 (12800 B)   conflict-free b128 reads
//   k_s  [208][40] @12800 (16640) conflict-free
//   P_s  [64][216] @12800 (27648) overlays k_s post-QK
// Q direct to A-frag regs. Bias arrives as pre-arranged C-frags (biasp2),
// mask baked in as -1e30 => QK is mfma(aq,bk,cb). P unnormalized; 1/sum
// applied to the 8 output values.
__global__ __launch_bounds__(256, 4)
void attn_kernel(const char* __restrict__ kv2, const char* __restrict__ qb2,
                 const float* __restrict__ biasp2, bf16* __restrict__ aout) {
  __shared__ __attribute__((aligned(16))) char smem[40448];
  bf16* vT_s = (bf16*)smem;            // [32][200]
  bf16* k_s  = (bf16*)(smem + 12800);  // [208][40], cols 0-15 data, 16-31 zero
  bf16* P_s  = (bf16*)(smem + 12800);  // [64][216] overlay (post-QK)

  const int bh = blockIdx.x;
  const int b = bh / 12;
  const int h = bh - b * 12;
  const int tid  = threadIdx.x;
  const int lane = tid & 63;
  const int wid  = tid >> 6;
  const int mrow = lane & 15;
  const int quad = lane >> 4;

  const bf16* ksrc = (const bf16*)(kv2 + (long)bh * KV2_BLK);
  const bf16* vsrc = (const bf16*)(kv2 + (long)bh * KV2_BLK + KV2_VOFF);
  const bf16* qsrc = (const bf16*)(qb2 + (long)bh * Q2_BLK);

  bf16x8 z = {};
  // Q A-fragment + bias C-frags issued first (coalesced; latency hides
  // under the LDS staging below).
  const int qrow = wid * 16 + mrow;
  bf16x8 aq = (quad < 2 && qrow < 49)
                  ? *(const bf16x8*)(qsrc + qrow * 16 + quad * 8) : z;
  f32x4 cb[13];
  {
    const f32x4* bf2 = (const f32x4*)biasp2 + ((long)(h * 4 + wid) * 13 * 64 + lane);
#pragma unroll
    for (int jt = 0; jt < 13; ++jt) cb[jt] = bf2[jt * 64];
  }

  {
    // k: 208 rows x 4 chunks of bf16x8 (cols 16-31 zeroed, 32-39 unread)
    for (int i = tid; i < 832; i += 256) {
      int r = i >> 2, c = i & 3;
      *(bf16x8*)(k_s + r * 40 + c * 8) =
          (r < 196 && c < 2) ? *(const bf16x8*)(ksrc + r * 16 + c * 8) : z;
    }
    // vT: 32 rows x 50 chunks of bf16x4 (cols 196-199 zeroed)
    bf16x4 z4 = {};
    for (int i = tid; i < 1600; i += 256) {
      int r = i / 50, c = i - r * 50;
      *(bf16x4*)(vT_s + r * 200 + c * 4) =
          (c < 49) ? *(const bf16x4*)(vsrc + r * 196 + c * 4) : z4;
    }
  }
  __syncthreads();

  // QK^T: 13 n-tiles of 16 keys, bias as C-in (mask included)
  f32x4 s[13];
#pragma unroll
  for (int jt = 0; jt < 13; ++jt) {
    bf16x8 bk = *(const bf16x8*)(k_s + (jt * 16 + mrow) * 40 + quad * 8);
    s[jt] = __builtin_amdgcn_mfma_f32_16x16x32_bf16(aq, bk, cb[jt], 0, 0, 0);
  }

  const int rbase = wid * 16 + quad * 4;
  float mx[4], sm[4];
#pragma unroll
  for (int reg = 0; reg < 4; ++reg) {
    float m = -1e30f;
#pragma unroll
    for (int jt = 0; jt < 13; ++jt) m = fmaxf(m, s[jt][reg]);
    m = fmaxf(m, __shfl_xor(m, 1));
    m = fmaxf(m, __shfl_xor(m, 2));
    m = fmaxf(m, __shfl_xor(m, 4));
    m = fmaxf(m, __shfl_xor(m, 8));
    mx[reg] = m;
  }
#pragma unroll
  for (int jt = 0; jt < 13; ++jt)
#pragma unroll
    for (int reg = 0; reg < 4; ++reg)
      s[jt][reg] = __builtin_amdgcn_exp2f(s[jt][reg] - mx[reg]);  // masked -> 0
#pragma unroll
  for (int reg = 0; reg < 4; ++reg) {
    float t = 0.0f;
#pragma unroll
    for (int jt = 0; jt < 13; ++jt) t += s[jt][reg];
    t += __shfl_xor(t, 1);
    t += __shfl_xor(t, 2);
    t += __shfl_xor(t, 4);
    t += __shfl_xor(t, 8);
    sm[reg] = 1.0f / t;
  }

  __syncthreads();  // all waves done with k_s before P overlay writes

  // P (unnormalized): cols 0-207 written (196-207 are exp2(masked) = 0)
  bf16* Pw = P_s + wid * 16 * 216;
#pragma unroll
  for (int jt = 0; jt < 13; ++jt) {
#pragma unroll
    for (int reg = 0; reg < 4; ++reg)
      Pw[(quad * 4 + reg) * 216 + jt * 16 + mrow] = (bf16)s[jt][reg];
  }

  f32x4 o[2] = {};
#pragma unroll
  for (int kk = 0; kk < 6; ++kk) {
    bf16x8 ap = *(const bf16x8*)(Pw + mrow * 216 + kk * 32 + quad * 8);
#pragma unroll
    for (int nt = 0; nt < 2; ++nt) {
      bf16x8 bv = *(const bf16x8*)(vT_s + (nt * 16 + mrow) * 200 + kk * 32 + quad * 8);
      o[nt] = __builtin_amdgcn_mfma_f32_16x16x32_bf16(ap, bv, o[nt], 0, 0, 0);
    }
  }
  {  // kk=6: keys 192-199 only (quad 0); other quads contribute zero
    bf16x8 ap = (quad == 0) ? *(const bf16x8*)(Pw + mrow * 216 + 192) : z;
#pragma unroll
    for (int nt = 0; nt < 2; ++nt) {
      bf16x8 bv = (quad == 0) ? *(const bf16x8*)(vT_s + (nt * 16 + mrow) * 200 + 192) : z;
      o[nt] = __builtin_amdgcn_mfma_f32_16x16x32_bf16(ap, bv, o[nt], 0, 0, 0);
    }
  }

#pragma unroll
  for (int nt = 0; nt < 2; ++nt) {
#pragma unroll
    for (int reg = 0; reg < 4; ++reg) {
      int r = rbase + reg;
      if (r < 49) {
        float x = o[nt][reg] * sm[reg];   // normalization folded here
        float sil = x / (1.0f + __expf(-x));
        aout[((long)b * 49 + r) * 384 + h * 32 + nt * 16 + mrow] = (bf16)sil;
      }
    }
  }
}

// ---------------------------------------------------------------------------
extern "C" void kernel_launch(void* const* d_in, const int* in_sizes, int n_in,
                              void* d_out, int out_size, void* d_ws, size_t ws_size,
                              hipStream_t stream) {
  const float* x      = (const float*)d_in[0];
  const float* kv_w   = (const float*)d_in[1];
  const float* q_w    = (const float*)d_in[6];
  const float* pj_w   = (const float*)d_in[11];
  const float* biases = (const float*)d_in[16];
  const int*   bidx   = (const int*)d_in[17];

  char* ws = (char*)d_ws;
  float* scbuf = (float*)ws;                  // 2560 f32
  char*  qb2   = ws + 471296;                 // 3072 x 1568 B
  bf16*  aout  = (bf16*)(ws + 5288192);       // (12544,384) bf16
  bf16*  xb    = (bf16*)(ws + 14921984);      // (50176,384) bf16 = 38.5 MB
  bf16*  kvwb  = (bf16*)(ws + 53457152);      // (576,384) bf16
  bf16*  qwb   = (bf16*)(ws + 53899520);      // (192,384) bf16
  bf16*  pjwb  = (bf16*)(ws + 54046976);      // (512,384) bf16
  char*  kv2   = ws + 54440192;               // 3072 x 18816 B = 57.8 MB
  float* biasp2= (float*)(ws + 112242944);    // 39936 f32x4 = 639 KB
                                              // end: ~112.9 MB (< ~300 MB ws)

  // stage 1: all casts + BN-fold + bias pre-arrange in ONE dispatch
  setup_kernel<<<9809, 256, 0, stream>>>(
      x, xb, kv_w, q_w, pj_w, kvwb, qwb, pjwb,
      (const float*)d_in[2],  (const float*)d_in[3],  (const float*)d_in[4],  (const float*)d_in[5],
      (const float*)d_in[7],  (const float*)d_in[8],  (const float*)d_in[9],  (const float*)d_in[10],
      (const float*)d_in[12], (const float*)d_in[13], (const float*)d_in[14], (const float*)d_in[15],
      scbuf, biases, bidx, biasp2);

  // stage 2: kv + q GEMMs in ONE dispatch (y<9: kv; y>=9: q, x<98)
  gemm_bn_kernel<<<dim3(392, 12), 128, 0, stream>>>(
      1, xb, kvwb, qwb, scbuf, scbuf + 576, scbuf + 1152, scbuf + 1344,
      kv2, qb2, 0);

  // stage 3: fused attention per (b,h)
  attn_kernel<<<3072, 256, 0, stream>>>(kv2, qb2, biasp2, aout);

  // stage 4: out = BN(silu_attn @ pj_w^T), fp32 out
  gemm_bn_kernel<<<dim3(98, 8), 128, 0, stream>>>(
      0, aout, pjwb, (const bf16*)nullptr, scbuf + 1536, scbuf + 2048,
      (const float*)nullptr, (const float*)nullptr, (char*)d_out,
      (char*)nullptr, 512);
}